// Round 9
// baseline (158.345 us; speedup 1.0000x reference)
//
#include <hip/hip_runtime.h>

#define LN 4096
#define DN 150
#define NT 10          // d padded to 10 x 16 tiles
#define KSPLIT 8
#define KQ (LN / KSPLIT)   // 512 k per block
#define KS 128             // k per LDS slice
#define NSS (KQ / KS)      // 4 slices

typedef __attribute__((ext_vector_type(8))) short bf16x8;
typedef __attribute__((ext_vector_type(4))) float f32x4;

// round-to-nearest-even fp32 -> bf16 (finite inputs only)
__device__ __forceinline__ unsigned int f2bf(float f) {
    unsigned int u = __builtin_bit_cast(unsigned int, f);
    u = (u + 0x7FFFu + ((u >> 16) & 1u)) >> 16;
    return u & 0xFFFFu;
}

__global__ __launch_bounds__(256) void k_zero(f32x4* __restrict__ p, int n4) {
    int i = blockIdx.x * 256 + threadIdx.x;
    if (i < n4) p[i] = (f32x4){0.f, 0.f, 0.f, 0.f};
}

// h [4096][150] f32  ->  Ht [160][4096] bf16 (rows 150..159 zero)
__global__ __launch_bounds__(256) void k_transpose(const float* __restrict__ h,
                                                   unsigned short* __restrict__ Ht) {
    __shared__ float S[64][33];
    const int i0 = blockIdx.x * 64;
    const int d0 = blockIdx.y * 32;
    const int tid = threadIdx.x;
    for (int t = tid; t < 64 * 32; t += 256) {
        int ii = t >> 5, dd = t & 31;
        int d = d0 + dd;
        S[ii][dd] = (d < DN) ? h[(size_t)(i0 + ii) * DN + d] : 0.0f;
    }
    __syncthreads();
    for (int t = tid; t < 32 * 64; t += 256) {
        int dd = t >> 6, ii = t & 63;
        Ht[(size_t)(d0 + dd) * LN + i0 + ii] = (unsigned short)f2bf(S[ii][dd]);
    }
}

// TR=0 (h_out): out[m0+r][d] += sum_k bf16(adj[m][k][0]+adj[m][k][1]) * Hbf[k][d]
// TR=1 (h_in):  out[m0+j][d]  += sum_i bf16(adj[i][j][0]+adj[i][j][1]) * Hbf[i][d]
// M-tile 64, per-wave m-tile 16 over full block k-range; KSPLIT partials via atomicAdd.
template <int TR>
__global__ __launch_bounds__(256, 2) void k_gemm(const float* __restrict__ adj,
                                                 const unsigned short* __restrict__ Ht,
                                                 float* __restrict__ out) {
    __shared__ unsigned int At[2][64 * 64];  // [row][64 u32 = 128 k bf16], swizzled; 2x16KB
    const int tid  = threadIdx.x;
    const int lane = tid & 63;
    const int wave = tid >> 6;
    const int r16  = lane & 15;
    const int g    = lane >> 4;
    const int m0 = blockIdx.x * 64;
    const int kq = blockIdx.y * KQ;

    f32x4 acc[NT];
    #pragma unroll
    for (int n = 0; n < NT; ++n) acc[n] = (f32x4){0.f, 0.f, 0.f, 0.f};

    f32x4 sv[16];  // staging registers (issue-early / write-late)

    auto stage_load = [&](int ss) {
        const int kb = kq + ss * KS;
        if (TR == 0) {
            #pragma unroll
            for (int rr = 0; rr < 16; ++rr) {
                int rl = rr * 4 + (tid >> 6);
                sv[rr] = *reinterpret_cast<const f32x4*>(
                    adj + ((size_t)(m0 + rl) * LN + kb) * 2 + (tid & 63) * 4);
            }
        } else {
            #pragma unroll
            for (int rr = 0; rr < 8; ++rr) {
                int ip = rr * 8 + (tid >> 5);
                size_t base = ((size_t)(kb + 2 * ip) * LN + m0 + 2 * (tid & 31)) * 2;
                sv[2 * rr]     = *reinterpret_cast<const f32x4*>(adj + base);
                sv[2 * rr + 1] = *reinterpret_cast<const f32x4*>(adj + base + 2 * LN);
            }
        }
    };
    auto stage_write = [&](int buf) {
        if (TR == 0) {
            const int kk = tid & 63;
            #pragma unroll
            for (int rr = 0; rr < 16; ++rr) {
                int rl = rr * 4 + (tid >> 6);
                unsigned int u = f2bf(sv[rr].x + sv[rr].y) | (f2bf(sv[rr].z + sv[rr].w) << 16);
                At[buf][rl * 64 + (((kk >> 2) ^ ((rl >> 1) & 15)) & 15) * 4 + (kk & 3)] = u;
            }
        } else {
            const int jA = 2 * (tid & 31), jB = jA + 1;
            #pragma unroll
            for (int rr = 0; rr < 8; ++rr) {
                int ip = rr * 8 + (tid >> 5);
                f32x4 v0 = sv[2 * rr], v1 = sv[2 * rr + 1];
                unsigned int uA = f2bf(v0.x + v0.y) | (f2bf(v1.x + v1.y) << 16);
                unsigned int uB = f2bf(v0.z + v0.w) | (f2bf(v1.z + v1.w) << 16);
                int bs = ((ip >> 2) ^ ((jA >> 1) & 15)) & 15;  // jA>>1 == jB>>1
                At[buf][jA * 64 + bs * 4 + (ip & 3)] = uA;
                At[buf][jB * 64 + bs * 4 + (ip & 3)] = uB;
            }
        }
    };
    auto frag = [&](int buf, int s) {
        int row = wave * 16 + r16;
        int blk = s * 4 + g;
        return *reinterpret_cast<const bf16x8*>(
            &At[buf][row * 64 + ((blk ^ ((row >> 1) & 15)) & 15) * 4]);
    };

    stage_load(0);
    stage_write(0);
    __syncthreads();
    #pragma unroll 2
    for (int ss = 0; ss < NSS; ++ss) {
        const int buf = ss & 1;
        if (ss + 1 < NSS) stage_load(ss + 1);  // issue next slice's loads under compute
        #pragma unroll
        for (int s = 0; s < 4; ++s) {
            const int k = kq + ss * KS + s * 32 + g * 8;
            bf16x8 B[NT];
            #pragma unroll
            for (int n = 0; n < NT; ++n)
                B[n] = *reinterpret_cast<const bf16x8*>(Ht + (size_t)(n * 16 + r16) * LN + k);
            bf16x8 a = frag(buf, s);
            #pragma unroll
            for (int n = 0; n < NT; ++n)
                acc[n] = __builtin_amdgcn_mfma_f32_16x16x32_bf16(a, B[n], acc[n], 0, 0, 0);
        }
        __syncthreads();                       // all waves done reading buf
        if (ss + 1 < NSS) stage_write(buf ^ 1);
        __syncthreads();                       // writes visible before next slice's reads
    }

    // epilogue: direct atomic combine (C: col=lane&15, row=(lane>>4)*4+reg)
    #pragma unroll
    for (int n = 0; n < NT; ++n) {
        #pragma unroll
        for (int q = 0; q < 4; ++q) {
            int row = m0 + wave * 16 + g * 4 + q;
            int col = n * 16 + r16;
            if (col < DN) atomicAdd(&out[(size_t)row * DN + col], acc[n][q]);
        }
    }
}

extern "C" void kernel_launch(void* const* d_in, const int* in_sizes, int n_in,
                              void* d_out, int out_size, void* d_ws, size_t ws_size,
                              hipStream_t stream) {
    const float* adj = (const float*)d_in[0];
    const float* h   = (const float*)d_in[1];
    float* out = (float*)d_out;
    unsigned short* Ht = (unsigned short*)d_ws;  // 160*4096*2 = 1.31 MB scratch

    const int n4 = out_size / 4;
    k_zero<<<(n4 + 255) / 256, 256, 0, stream>>>((f32x4*)out, n4);
    k_transpose<<<dim3(64, 5), 256, 0, stream>>>(h, Ht);
    // d_out layout: [h_in (L*D) | h_out (L*D)]
    k_gemm<0><<<dim3(64, KSPLIT), 256, 0, stream>>>(adj, Ht, out + (size_t)LN * DN); // h_out
    k_gemm<1><<<dim3(64, KSPLIT), 256, 0, stream>>>(adj, Ht, out);                   // h_in
}

// Round 10
// 100.129 us; speedup vs baseline: 1.5814x; 1.5814x over previous
//
#include <hip/hip_runtime.h>

#define LN 4096
#define DN 150
#define NT 10          // d padded to 10 x 16 tiles
#define KSPLIT 4
#define KQ 1024        // k per block
#define NSS 4          // super-steps of 256 k

typedef __attribute__((ext_vector_type(8))) short bf16x8;
typedef __attribute__((ext_vector_type(4))) float f32x4;

// round-to-nearest-even fp32 -> bf16 (finite inputs only)
__device__ __forceinline__ unsigned short f2bf(float f) {
    unsigned int u = __builtin_bit_cast(unsigned int, f);
    u = (u + 0x7FFFu + ((u >> 16) & 1u)) >> 16;
    return (unsigned short)u;
}

__global__ __launch_bounds__(256) void k_zero(f32x4* __restrict__ p, int n4) {
    int i = blockIdx.x * 256 + threadIdx.x;
    if (i < n4) p[i] = (f32x4){0.f, 0.f, 0.f, 0.f};
}

// h [4096][150] f32  ->  Ht [160][4096] bf16 (rows 150..159 zero)
__global__ __launch_bounds__(256) void k_transpose(const float* __restrict__ h,
                                                   unsigned short* __restrict__ Ht) {
    __shared__ float S[64][33];
    const int i0 = blockIdx.x * 64;
    const int d0 = blockIdx.y * 32;
    const int tid = threadIdx.x;
    for (int t = tid; t < 64 * 32; t += 256) {
        int ii = t >> 5, dd = t & 31;
        int d = d0 + dd;
        S[ii][dd] = (d < DN) ? h[(size_t)(i0 + ii) * DN + d] : 0.0f;
    }
    __syncthreads();
    for (int t = tid; t < 32 * 64; t += 256) {
        int dd = t >> 6, ii = t & 63;
        Ht[(size_t)(d0 + dd) * LN + i0 + ii] = f2bf(S[ii][dd]);
    }
}

// out[i] = sum_k pIn[k][i] (h_in half), and same for pOut into the h_out half.
__global__ __launch_bounds__(256) void k_reduce(const float* __restrict__ pIn,
                                                const float* __restrict__ pOut,
                                                float* __restrict__ out, int n4) {
    int i = blockIdx.x * 256 + threadIdx.x;
    if (i >= n4) return;
    const f32x4* a = reinterpret_cast<const f32x4*>(pIn);
    const f32x4* b = reinterpret_cast<const f32x4*>(pOut);
    f32x4 s0 = a[i], s1 = b[i];
    #pragma unroll
    for (int k = 1; k < KSPLIT; ++k) {
        s0 += a[(size_t)k * n4 + i];
        s1 += b[(size_t)k * n4 + i];
    }
    reinterpret_cast<f32x4*>(out)[i] = s0;             // h_in
    reinterpret_cast<f32x4*>(out)[n4 + i] = s1;        // h_out
}

// TR=0 (h_out): partial[m0+row][d] = sum_{k in block range} bf16(adj[m][k][0]+adj[m][k][1]) * Hbf[k][d]
// TR=1 (h_in):  partial[m0+row=j][d] = sum_i bf16(adj[i][j][0]+adj[i][j][1]) * Hbf[i][d]
// part!=nullptr: store per-KSPLIT partial (contiguous). part==nullptr: atomicAdd into pre-zeroed out.
template <int TR>
__global__ __launch_bounds__(256, 2) void k_gemm(const float* __restrict__ adj,
                                                 const unsigned short* __restrict__ Ht,
                                                 float* __restrict__ part,
                                                 float* __restrict__ out) {
    __shared__ unsigned short At[2][32 * 256];  // [row][256 k] bf16, XOR-swizzled, dbuf (32 KB)
    __shared__ float red[32][160];              // cross-wave reduce (20 KB)
    const int tid  = threadIdx.x;
    const int lane = tid & 63;
    const int wave = tid >> 6;
    const int r16  = lane & 15;  // A row / B col / C col within 16-tile
    const int g    = lane >> 4;  // k-group
    const int m0 = blockIdx.x * 32;
    const int kq = blockIdx.y * KQ;

    f32x4 acc[2][NT];
    #pragma unroll
    for (int mt = 0; mt < 2; ++mt)
        #pragma unroll
        for (int n = 0; n < NT; ++n) acc[mt][n] = (f32x4){0.f, 0.f, 0.f, 0.f};

    f32x4 sv[16];  // staging registers (issue-early / write-late)

    auto stage_load = [&](int ss) {
        if (TR == 0) {
            const int row = tid >> 7;    // 2 rows per round
            const int kk  = tid & 127;   // k-pair
            #pragma unroll
            for (int rr = 0; rr < 16; ++rr) {
                int rowr = rr * 2 + row;
                sv[rr] = *reinterpret_cast<const f32x4*>(
                    adj + ((size_t)(m0 + rowr) * LN + kq + ss * 256 + 2 * kk) * 2);
            }
        } else {
            const int iof = tid >> 4;    // 16 i-rows per round
            const int jp  = tid & 15;    // j-pair
            #pragma unroll
            for (int rr = 0; rr < 16; ++rr) {
                int il = rr * 16 + iof;
                sv[rr] = *reinterpret_cast<const f32x4*>(
                    adj + ((size_t)(kq + ss * 256 + il) * LN + m0 + jp * 2) * 2);
            }
        }
    };
    auto stage_write = [&](int buf) {
        if (TR == 0) {
            const int row = tid >> 7;
            const int kk  = tid & 127;
            #pragma unroll
            for (int rr = 0; rr < 16; ++rr) {
                int rowr = rr * 2 + row;
                unsigned int u = (unsigned int)f2bf(sv[rr].x + sv[rr].y) |
                                 ((unsigned int)f2bf(sv[rr].z + sv[rr].w) << 16);
                *reinterpret_cast<unsigned int*>(
                    &At[buf][rowr * 256 + ((2 * kk) ^ ((rowr & 15) << 3))]) = u;
            }
        } else {
            const int iof = tid >> 4;
            const int jA  = (tid & 15) * 2, jB = jA + 1;
            #pragma unroll
            for (int rr = 0; rr < 16; ++rr) {
                int k = rr * 16 + iof;
                At[buf][jA * 256 + (k ^ ((jA & 15) << 3))] = f2bf(sv[rr].x + sv[rr].y);
                At[buf][jB * 256 + (k ^ ((jB & 15) << 3))] = f2bf(sv[rr].z + sv[rr].w);
            }
        }
    };
    auto frag = [&](int buf, int mt, int s) {
        int row  = mt * 16 + r16;
        int kloc = wave * 64 + s * 32 + g * 8;  // wave owns k-slice of 64 per super-step
        return *reinterpret_cast<const bf16x8*>(&At[buf][row * 256 + (kloc ^ (r16 << 3))]);
    };
    auto loadB = [&](bf16x8 (&bb)[NT], int ss, int s) {
        int k = kq + ss * 256 + wave * 64 + s * 32 + g * 8;
        #pragma unroll
        for (int n = 0; n < NT; ++n)
            bb[n] = *reinterpret_cast<const bf16x8*>(Ht + (size_t)(n * 16 + r16) * LN + k);
    };

    stage_load(0);
    stage_write(0);
    __syncthreads();
    for (int ss = 0; ss < NSS; ++ss) {
        const int buf = ss & 1;
        if (ss + 1 < NSS) stage_load(ss + 1);  // issue next tile's loads under compute
        #pragma unroll
        for (int s = 0; s < 2; ++s) {
            bf16x8 B[NT];
            loadB(B, ss, s);
            bf16x8 a0 = frag(buf, 0, s);
            bf16x8 a1 = frag(buf, 1, s);
            #pragma unroll
            for (int n = 0; n < NT; ++n) {
                acc[0][n] = __builtin_amdgcn_mfma_f32_16x16x32_bf16(a0, B[n], acc[0][n], 0, 0, 0);
                acc[1][n] = __builtin_amdgcn_mfma_f32_16x16x32_bf16(a1, B[n], acc[1][n], 0, 0, 0);
            }
        }
        __syncthreads();                        // all waves done reading buf^1 (prev iter)
        if (ss + 1 < NSS) stage_write(buf ^ 1);
        __syncthreads();                        // writes visible before next iter's reads
    }

    // cross-wave K reduction (waves hold k-slices)
    for (int w4 = 0; w4 < 4; ++w4) {
        if (wave == w4) {
            #pragma unroll
            for (int mt = 0; mt < 2; ++mt)
                #pragma unroll
                for (int n = 0; n < NT; ++n)
                    #pragma unroll
                    for (int q = 0; q < 4; ++q) {
                        int row = mt * 16 + g * 4 + q;  // C: col=lane&15, row=(lane>>4)*4+q
                        if (w4 == 0) red[row][n * 16 + r16]  = acc[mt][n][q];
                        else         red[row][n * 16 + r16] += acc[mt][n][q];
                    }
        }
        __syncthreads();
    }
    if (part) {
        // contiguous partial store — no atomics, no contention
        float* dst = part + (size_t)blockIdx.y * (LN * DN);
        for (int t2 = tid; t2 < 32 * DN; t2 += 256) {
            int row = t2 / DN, col = t2 % DN;
            dst[(size_t)(m0 + row) * DN + col] = red[row][col];
        }
    } else {
        for (int t2 = tid; t2 < 32 * DN; t2 += 256) {
            int row = t2 / DN, col = t2 % DN;
            atomicAdd(&out[(size_t)(m0 + row) * DN + col], red[row][col]);
        }
    }
}

extern "C" void kernel_launch(void* const* d_in, const int* in_sizes, int n_in,
                              void* d_out, int out_size, void* d_ws, size_t ws_size,
                              hipStream_t stream) {
    const float* adj = (const float*)d_in[0];
    const float* h   = (const float*)d_in[1];
    float* out = (float*)d_out;
    char* ws = (char*)d_ws;

    unsigned short* Ht = (unsigned short*)ws;                    // 1.31 MB @ 0
    const size_t offPin  = 2u << 20;                             // h_in partials @ 2 MB
    const size_t psz     = (size_t)KSPLIT * LN * DN * 4;         // 9.83 MB
    const size_t offPout = offPin + psz;
    const size_t need    = offPout + psz;                        // ~21.7 MB

    k_transpose<<<dim3(64, 5), 256, 0, stream>>>(h, Ht);

    if (ws_size >= need) {
        float* pIn  = (float*)(ws + offPin);
        float* pOut = (float*)(ws + offPout);
        k_gemm<0><<<dim3(128, KSPLIT), 256, 0, stream>>>(adj, Ht, pOut, nullptr); // h_out
        k_gemm<1><<<dim3(128, KSPLIT), 256, 0, stream>>>(adj, Ht, pIn,  nullptr); // h_in
        const int n4 = (LN * DN) / 4;  // 153600
        k_reduce<<<(n4 + 255) / 256, 256, 0, stream>>>(pIn, pOut, out, n4);
    } else {
        const int n4 = out_size / 4;
        k_zero<<<(n4 + 255) / 256, 256, 0, stream>>>((f32x4*)out, n4);
        k_gemm<0><<<dim3(128, KSPLIT), 256, 0, stream>>>(adj, Ht, nullptr, out + (size_t)LN * DN);
        k_gemm<1><<<dim3(128, KSPLIT), 256, 0, stream>>>(adj, Ht, nullptr, out);
    }
}